// Round 4
// baseline (373.042 us; speedup 1.0000x reference)
//
#include <hip/hip_runtime.h>
#include <math.h>

#define EPS 1e-12f

typedef unsigned short ushort_t;
typedef __attribute__((ext_vector_type(8))) short short8;
typedef __attribute__((ext_vector_type(4))) float f32x4;
typedef __attribute__((ext_vector_type(4))) unsigned short ushort4v;

// ---- workspace layout (float units) ----
// 0       : Wb   192x256 bf16 (theta rows 0..31, phi 32..63, g 64..191) = 24576 f
// 24576   : Wo_b 256x128 bf16 = 16384 f
// 40960   : theta_b [n][l][32c]  bf16 (16*4096*32)  = 1048576 f
// 1089536 : phi_b   [n][m][32c]  bf16 (16*1024*32)  = 262144 f
// 1351680 : g_b     [n][cg][m]   bf16 (16*128*1024) = 1048576 f
// xT (x transposed to bf16 [n][l][256c], 33.5 MB) lives in the FRONT of d_out
// (scratch until attn_mfma overwrites d_out with the final result).
#define WS_WB_F 0
#define WS_WO_F 24576
#define WS_TH_F 40960
#define WS_PH_F 1089536
#define WS_G_F  1351680

__device__ __forceinline__ ushort_t f2bf(float f) {
  unsigned int u = __float_as_uint(f);
  u += 0x7fffu + ((u >> 16) & 1u);
  return (ushort_t)(u >> 16);
}

__device__ __forceinline__ float block_reduce_sum(float v, float* red) {
  int t = threadIdx.x;
  red[t] = v;
  __syncthreads();
  #pragma unroll
  for (int s = 128; s > 0; s >>= 1) {
    if (t < s) red[t] += red[t + s];
    __syncthreads();
  }
  float r = red[0];
  __syncthreads();
  return r;
}

// One block per weight: spectral-norm scale, emit bf16 weights.
__global__ __launch_bounds__(256) void sn_kernel(
    const float* __restrict__ Wt, const float* __restrict__ Wp,
    const float* __restrict__ Wg, const float* __restrict__ Wo,
    const float* __restrict__ ut, const float* __restrict__ up,
    const float* __restrict__ ug, const float* __restrict__ uo,
    float* __restrict__ ws) {
  __shared__ float red[256];
  __shared__ float ub[256];
  __shared__ float vb[256];
  const float* W; const float* u; int O, Ci;
  switch (blockIdx.x) {
    case 0:  W = Wt; u = ut; O = 32;  Ci = 256; break;
    case 1:  W = Wp; u = up; O = 32;  Ci = 256; break;
    case 2:  W = Wg; u = ug; O = 128; Ci = 256; break;
    default: W = Wo; u = uo; O = 256; Ci = 128; break;
  }
  int t = threadIdx.x;
  if (t < O) ub[t] = u[t];
  __syncthreads();
  float tv = 0.f;
  if (t < Ci) {
    for (int o = 0; o < O; o++) tv += W[o * Ci + t] * ub[o];
  }
  float nt2 = block_reduce_sum((t < Ci) ? tv * tv : 0.f, red);
  float ntn = sqrtf(nt2);
  if (t < Ci) vb[t] = tv / (ntn + EPS);
  __syncthreads();
  float sv = 0.f;
  if (t < O) {
    for (int c = 0; c < Ci; c++) sv += W[t * Ci + c] * vb[c];
  }
  float ss = block_reduce_sum((t < O) ? sv * sv : 0.f, red);
  float ns = sqrtf(ss);
  float sigma = ss / (ns + EPS);
  float inv = 1.f / sigma;
  int total = O * Ci;
  ushort_t* dst;
  if (blockIdx.x == 3)      dst = (ushort_t*)(ws + WS_WO_F);
  else if (blockIdx.x == 0) dst = (ushort_t*)(ws + WS_WB_F);
  else if (blockIdx.x == 1) dst = (ushort_t*)(ws + WS_WB_F) + 32 * 256;
  else                      dst = (ushort_t*)(ws + WS_WB_F) + 64 * 256;
  for (int i = t; i < total; i += 256) dst[i] = f2bf(W[i] * inv);
}

// x [n][c][l] fp32  ->  xT [n][l][256c] bf16 (pure transpose+convert, no LDS).
__global__ __launch_bounds__(256) void xpose_kernel(const float* __restrict__ x,
                                                    ushort_t* __restrict__ xT) {
  const int t = threadIdx.x;
  const int n = blockIdx.y;
  const int l = blockIdx.x * 128 + (t & 127);
  const int half = t >> 7;
  const float* xp = x + ((size_t)n * 256) * 4096 + l;
  ushort_t* op = xT + ((size_t)n * 4096 + l) * 256;
  #pragma unroll 4
  for (int it = 0; it < 16; ++it) {
    int oct = it * 2 + half;
    short8 v;
    #pragma unroll
    for (int j = 0; j < 8; ++j) v[j] = (short)f2bf(xp[(size_t)(oct * 8 + j) * 4096]);
    *(short8*)(op + oct * 8) = v;
  }
}

// Projection GEMM + fused 2x2 maxpool. Weights register-resident per wave
// (wave w owns out-channel groups {3w,3w+1,3w+2}); B-frags read directly from
// xT (native [l][c] layout, 16B/lane). Block = (row-pair h, n): 128 px.
__global__ __launch_bounds__(256, 2) void proj_gemm(
    const ushort_t* __restrict__ xT, const ushort_t* __restrict__ wb,
    ushort_t* __restrict__ theta_b, ushort_t* __restrict__ phi_b,
    ushort_t* __restrict__ g_b) {
  const int t = threadIdx.x;
  const int w = t >> 6;
  const int lane = t & 63;
  const int quad = lane >> 4;
  const int l16 = lane & 15;
  const int n = blockIdx.y;
  const int h = blockIdx.x;          // pooled row index (rows 2h, 2h+1)
  const int l0 = h * 128;

  short8 wA[3][8];
  #pragma unroll
  for (int i = 0; i < 3; ++i) {
    int mtg = w * 3 + i;
    #pragma unroll
    for (int kc = 0; kc < 8; ++kc)
      wA[i][kc] = *(const short8*)(wb + (size_t)(mtg * 16 + l16) * 256 + kc * 32 + quad * 8);
  }
  const ushort_t* xb = xT + ((size_t)n * 4096 + l0) * 256;

  #pragma unroll 1
  for (int s = 0; s < 4; ++s) {
    const int pxA = s * 16 + l16;    // local px in row 2h; row 2h+1 is +64
    f32x4 accA[3], accB[3];
    #pragma unroll
    for (int i = 0; i < 3; ++i) {
      accA[i] = (f32x4){0.f, 0.f, 0.f, 0.f};
      accB[i] = (f32x4){0.f, 0.f, 0.f, 0.f};
    }
    #pragma unroll
    for (int kc = 0; kc < 8; ++kc) {
      short8 bA = *(const short8*)(xb + (size_t)pxA * 256 + kc * 32 + quad * 8);
      short8 bB = *(const short8*)(xb + (size_t)(pxA + 64) * 256 + kc * 32 + quad * 8);
      #pragma unroll
      for (int i = 0; i < 3; ++i) {
        accA[i] = __builtin_amdgcn_mfma_f32_16x16x32_bf16(wA[i][kc], bA, accA[i], 0, 0, 0);
        accB[i] = __builtin_amdgcn_mfma_f32_16x16x32_bf16(wA[i][kc], bB, accB[i], 0, 0, 0);
      }
    }
    #pragma unroll
    for (int i = 0; i < 3; ++i) {
      int mtg = w * 3 + i;
      if (mtg < 2) {
        ushort4v vA, vB;
        #pragma unroll
        for (int r = 0; r < 4; ++r) { vA[r] = f2bf(accA[i][r]); vB[r] = f2bf(accB[i][r]); }
        *(ushort4v*)(theta_b + ((size_t)n * 4096 + l0 + pxA) * 32 + mtg * 16 + quad * 4) = vA;
        *(ushort4v*)(theta_b + ((size_t)n * 4096 + l0 + pxA + 64) * 32 + mtg * 16 + quad * 4) = vB;
      } else {
        float pm[4];
        #pragma unroll
        for (int r = 0; r < 4; ++r) {
          float v = fmaxf(accA[i][r], accB[i][r]);  // vertical pool
          v = fmaxf(v, __shfl_xor(v, 1));           // horizontal pool
          pm[r] = v;
        }
        if ((l16 & 1) == 0) {
          int m = h * 32 + s * 8 + (l16 >> 1);
          if (mtg < 4) {
            ushort4v vv;
            #pragma unroll
            for (int r = 0; r < 4; ++r) vv[r] = f2bf(pm[r]);
            *(ushort4v*)(phi_b + ((size_t)n * 1024 + m) * 32 + (mtg - 2) * 16 + quad * 4) = vv;
          } else {
            #pragma unroll
            for (int r = 0; r < 4; ++r)
              g_b[((size_t)n * 128 + (mtg - 4) * 16 + quad * 4 + r) * 1024 + m] = f2bf(pm[r]);
          }
        }
      }
    }
  }
}

// Barrier-free flash attention, fixed-offset softmax (no max reduction).
// Block = 64 queries (4 waves x 16q), XCD-swizzled so each XCD works on 2 n's.
__global__ __launch_bounds__(256, 4) void attn_mfma(
    const float* __restrict__ x,
    const ushort_t* __restrict__ theta_b,
    const ushort_t* __restrict__ phi_b,
    const ushort_t* __restrict__ g_b,
    const ushort_t* __restrict__ Wo_b,
    const float* __restrict__ gamma_p,
    float* __restrict__ out) {
  __shared__ ushort_t Pw[4][16 * 40];    // per-wave P / O staging, pitch 40

  const int t = threadIdx.x;
  const int w = t >> 6;
  const int lane = t & 63;
  const int quad = lane >> 4;
  const int l16 = lane & 15;
  // XCD swizzle: assume round-robin block->XCD; each XCD sees only 2 n values.
  const int bx = blockIdx.x;
  const int xcd = bx & 7;
  const int slot = bx >> 3;
  const int n = xcd * 2 + (slot >> 6);
  const int l0 = (slot & 63) * 64;
  ushort_t* PwW = Pw[w];

  const short8 a_th = *(const short8*)(theta_b + ((size_t)n * 4096 + l0 + w * 16 + l16) * 32 + quad * 8);
  const ushort_t* phiN = phi_b + (size_t)n * 1024 * 32;
  const ushort_t* gN   = g_b + (size_t)n * 128 * 1024;

  f32x4 oacc[8];
  #pragma unroll
  for (int j = 0; j < 8; ++j) oacc[j] = (f32x4){0.f, 0.f, 0.f, 0.f};
  float Lacc[4] = {0.f, 0.f, 0.f, 0.f};

  #pragma unroll 1
  for (int mc = 0; mc < 32; ++mc) {
    const int m0 = mc * 32;
    short8 b0 = *(const short8*)(phiN + (size_t)(m0 + l16) * 32 + quad * 8);
    short8 b1 = *(const short8*)(phiN + (size_t)(m0 + 16 + l16) * 32 + quad * 8);
    short8 gf[8];
    #pragma unroll
    for (int j = 0; j < 8; ++j)
      gf[j] = *(const short8*)(gN + ((size_t)(j * 16 + l16)) * 1024 + m0 + quad * 8);
    f32x4 z = {0.f, 0.f, 0.f, 0.f};
    f32x4 s0 = __builtin_amdgcn_mfma_f32_16x16x32_bf16(a_th, b0, z, 0, 0, 0);
    f32x4 s1 = __builtin_amdgcn_mfma_f32_16x16x32_bf16(a_th, b1, z, 0, 0, 0);
    // fixed-offset exp: softmax is shift-invariant; logits bounded << 88.
    #pragma unroll
    for (int r = 0; r < 4; ++r) {
      float p0 = __expf(s0[r] - 16.f);
      float p1 = __expf(s1[r] - 16.f);
      Lacc[r] += p0 + p1;
      int q = quad * 4 + r;
      PwW[q * 40 + l16] = f2bf(p0);
      PwW[q * 40 + 16 + l16] = f2bf(p1);
    }
    short8 ap = *(const short8*)(PwW + l16 * 40 + quad * 8);
    #pragma unroll
    for (int j = 0; j < 8; ++j)
      oacc[j] = __builtin_amdgcn_mfma_f32_16x16x32_bf16(ap, gf[j], oacc[j], 0, 0, 0);
  }

  // single L reduction (within the 16-lane row group)
  float invL[4];
  #pragma unroll
  for (int r = 0; r < 4; ++r) {
    float L = Lacc[r];
    #pragma unroll
    for (int off = 8; off > 0; off >>= 1) L += __shfl_xor(L, off);
    invL[r] = 1.f / L;
  }

  // epilogue: D2[q][oc] = (O/L)[q][cg] . Wo[oc][cg]
  f32x4 acc2[16];
  #pragma unroll
  for (int i = 0; i < 16; ++i) acc2[i] = (f32x4){0.f, 0.f, 0.f, 0.f};
  #pragma unroll
  for (int kc = 0; kc < 4; ++kc) {
    #pragma unroll
    for (int r = 0; r < 4; ++r) {
      int q = quad * 4 + r;
      PwW[q * 40 + l16] = f2bf(oacc[2 * kc][r] * invL[r]);
      PwW[q * 40 + 16 + l16] = f2bf(oacc[2 * kc + 1][r] * invL[r]);
    }
    short8 aO = *(const short8*)(PwW + l16 * 40 + quad * 8);
    #pragma unroll
    for (int oct = 0; oct < 16; ++oct) {
      short8 bw = *(const short8*)(Wo_b + (size_t)(oct * 16 + l16) * 128 + kc * 32 + quad * 8);
      acc2[oct] = __builtin_amdgcn_mfma_f32_16x16x32_bf16(aO, bw, acc2[oct], 0, 0, 0);
    }
  }
  // direct residual stores: lane holds (oc = oct*16+l16, q = quad*4 + 0..3)
  {
    const float gm = gamma_p[0];
    #pragma unroll
    for (int oct = 0; oct < 16; ++oct) {
      int oc = oct * 16 + l16;
      const float* xp = x + ((size_t)n * 256 + oc) * 4096 + l0 + w * 16 + quad * 4;
      float* op = out + ((size_t)n * 256 + oc) * 4096 + l0 + w * 16 + quad * 4;
      float4 xv = *(const float4*)xp;
      float4 v;
      v.x = xv.x + gm * acc2[oct][0];
      v.y = xv.y + gm * acc2[oct][1];
      v.z = xv.z + gm * acc2[oct][2];
      v.w = xv.w + gm * acc2[oct][3];
      *(float4*)op = v;
    }
  }
}

extern "C" void kernel_launch(void* const* d_in, const int* in_sizes, int n_in,
                              void* d_out, int out_size, void* d_ws, size_t ws_size,
                              hipStream_t stream) {
  const float* x  = (const float*)d_in[0];
  const float* Wt = (const float*)d_in[1];
  const float* Wp = (const float*)d_in[2];
  const float* Wg = (const float*)d_in[3];
  const float* Wo = (const float*)d_in[4];
  const float* ut = (const float*)d_in[5];
  const float* up = (const float*)d_in[6];
  const float* ug = (const float*)d_in[7];
  const float* uo = (const float*)d_in[8];
  const float* gamma = (const float*)d_in[9];
  float* ws  = (float*)d_ws;
  float* out = (float*)d_out;

  ushort_t* wb      = (ushort_t*)(ws + WS_WB_F);
  ushort_t* Wo_b    = (ushort_t*)(ws + WS_WO_F);
  ushort_t* theta_b = (ushort_t*)(ws + WS_TH_F);
  ushort_t* phi_b   = (ushort_t*)(ws + WS_PH_F);
  ushort_t* g_b     = (ushort_t*)(ws + WS_G_F);
  ushort_t* xT      = (ushort_t*)d_out;   // scratch: overwritten by attn's output

  xpose_kernel<<<dim3(32, 16), 256, 0, stream>>>(x, xT);
  sn_kernel<<<4, 256, 0, stream>>>(Wt, Wp, Wg, Wo, ut, up, ug, uo, ws);
  proj_gemm<<<dim3(32, 16), 256, 0, stream>>>(xT, wb, theta_b, phi_b, g_b);
  attn_mfma<<<1024, 256, 0, stream>>>(x, theta_b, phi_b, g_b, Wo_b, gamma, out);
}